// Round 4
// baseline (57.808 us; speedup 1.0000x reference)
//
#include <hip/hip_runtime.h>

// MultiHuberLoss: input [65536, 1000] f32, target [65536] i32 -> scalar f32
//   m = (c == target[r]) ? x : -x
//   loss = (m >= -1) ? max(0, 1-m)^2 : -4*m
//   out = sum(loss) / 65536

typedef float f4 __attribute__((ext_vector_type(4)));     // native vec type: OK for nontemporal builtin

constexpr int N_ROWS = 65536;
constexpr int N_COLS = 1000;
constexpr int F4_PER_ROW = N_COLS / 4;                    // 250
constexpr int TOTAL_F4 = N_ROWS * F4_PER_ROW;             // 16,384,000

// grid chosen so stride is an exact multiple of a row:
// 2000*256 = 512,000 threads; 512,000 f4 = 2048 whole rows per stride;
// 16,384,000 / 512,000 = 32 iterations exactly (no tail, no bounds check).
constexpr int GRID = 2000;
constexpr int BLOCK = 256;
constexpr int STRIDE_F4 = GRID * BLOCK;                   // 512,000
constexpr int STRIDE_ROWS = STRIDE_F4 / F4_PER_ROW;       // 2048
constexpr int ITERS = TOTAL_F4 / STRIDE_F4;               // 32
constexpr int BATCH = 8;                                  // 16 VMEM / 8 KB in flight per wave

__global__ __launch_bounds__(BLOCK) void mhl_kernel(const f4* __restrict__ in,
                                                    const int* __restrict__ tgt,
                                                    float* __restrict__ out) {
    int idx = blockIdx.x * BLOCK + threadIdx.x;

    int row = idx / F4_PER_ROW;                           // one divide, outside loop
    int c0 = (idx - row * F4_PER_ROW) * 4;                // loop-invariant column base
    int p = idx;

    float acc = 0.0f;

#pragma unroll 1
    for (int it = 0; it < ITERS / BATCH; ++it) {
        f4 v[BATCH];
        int t[BATCH];
        // issue all 16 loads back-to-back (independent addresses) before compute
#pragma unroll
        for (int j = 0; j < BATCH; ++j) {
            // input is a 262 MB single-pass stream: non-temporal (no L2/L3 allocate)
            v[j] = __builtin_nontemporal_load(&in[p + j * STRIDE_F4]);
            t[j] = tgt[row + j * STRIDE_ROWS];            // normal (cached) load
        }
#pragma unroll
        for (int j = 0; j < BATCH; ++j) {
#pragma unroll
            for (int e = 0; e < 4; ++e) {
                float x = v[j][e];
                float m = (c0 + e == t[j]) ? x : -x;
                float h = fmaxf(0.0f, 1.0f - m);
                float l = (m >= -1.0f) ? h * h : -4.0f * m;
                acc += l;
            }
        }
        p += BATCH * STRIDE_F4;
        row += BATCH * STRIDE_ROWS;
    }

    // wave64 butterfly reduce
#pragma unroll
    for (int off = 32; off > 0; off >>= 1)
        acc += __shfl_down(acc, off, 64);

    __shared__ float wsum[BLOCK / 64];
    int wid = threadIdx.x >> 6;
    int lane = threadIdx.x & 63;
    if (lane == 0) wsum[wid] = acc;
    __syncthreads();

    if (threadIdx.x == 0) {
        float s = wsum[0] + wsum[1] + wsum[2] + wsum[3];
        atomicAdd(out, s * (1.0f / (float)N_ROWS));
    }
}

extern "C" void kernel_launch(void* const* d_in, const int* in_sizes, int n_in,
                              void* d_out, int out_size, void* d_ws, size_t ws_size,
                              hipStream_t stream) {
    const f4* in = (const f4*)d_in[0];
    const int* tgt = (const int*)d_in[1];
    float* out = (float*)d_out;

    // d_out is poisoned (0xAA) before timing and NOT re-poisoned between
    // replays — zero it every call (memset is graph-capture-safe).
    (void)hipMemsetAsync(out, 0, sizeof(float), stream);

    mhl_kernel<<<GRID, BLOCK, 0, stream>>>(in, tgt, out);
}